// Round 1
// baseline (308.128 us; speedup 1.0000x reference)
//
#include <hip/hip_runtime.h>

// Locally connected layer:
// out[b,o,h,w] = sum_{c,i,j} x[b,c,h+i,w+j] * W[o,c,h,w,i,j] + bias[o,h,w]
// x: [32,32,64,64] f32, W: [64,32,62,62,3,3] f32, bias: [64,62,62] f32
// out: [32,64,62,62] f32
//
// Memory-bound on the W stream (283 MB, used once). One 64-thread block per
// (o,h); thread = (wgroup of 4 w) x (bgroup of 8 batches). W is read once per
// wave (4 batch-groups broadcast the same address); all 32 batches accumulate
// in registers so W never re-streams from HBM.

#define C_  32
#define B_  32
#define O_  64
#define H_  64
#define W_  64
#define OH_ 62
#define OW_ 62

__global__ __launch_bounds__(64)
void lcl_kernel(const float* __restrict__ x,
                const float* __restrict__ Wt,
                const float* __restrict__ bias,
                float* __restrict__ out) {
    const int h  = blockIdx.x;      // 0..61
    const int o  = blockIdx.y;      // 0..63
    const int t  = threadIdx.x;     // 0..63
    const int wg = t & 15;          // w-group: w0 = 4*wg
    const int bg = t >> 4;          // batch-group: b0 = 8*bg
    const int w0 = wg * 4;
    const int b0 = bg * 8;
    const bool full = (wg < 15);    // wg==15 covers only w=60,61

    float acc[8][4];
#pragma unroll
    for (int bi = 0; bi < 8; ++bi)
#pragma unroll
        for (int wi = 0; wi < 4; ++wi) acc[bi][wi] = 0.f;

    // W flat idx = o*(C*OH*OW*9) + c*(OH*OW*9) + h*(OW*9) + w*9 + i*3 + j
    const long wcstride = (long)OH_ * OW_ * 9;           // 34596
    const long wbase0   = (long)o * C_ * wcstride + (long)h * (OW_ * 9) + (long)w0 * 9;
    // x flat idx = ((b*C + c)*H + (h+i))*W + col
    const long xbstride = (long)C_ * H_ * W_;            // 131072
    const long xcstride = (long)H_ * W_;                 // 4096
    const long xbase0   = (long)b0 * xbstride + (long)h * W_ + w0;

    for (int c = 0; c < C_; ++c) {
        // ---- load W: 36 floats (4 w positions x 9 taps), contiguous, 8B-aligned
        const float* wp = Wt + wbase0 + (long)c * wcstride;
        float wv[36];
#pragma unroll
        for (int q = 0; q < 18; ++q) {
            if (q < 9 || full) {
                float2 v = *reinterpret_cast<const float2*>(wp + 2 * q);
                wv[2 * q] = v.x; wv[2 * q + 1] = v.y;
            } else {
                wv[2 * q] = 0.f; wv[2 * q + 1] = 0.f;
            }
        }

        const float* xp = x + xbase0 + (long)c * xcstride;
#pragma unroll
        for (int bi = 0; bi < 8; ++bi) {
            const float* xb = xp + (long)bi * xbstride;
            float xr[3][6];
#pragma unroll
            for (int i = 0; i < 3; ++i) {
                const float* row = xb + i * W_;
                float4 v4 = *reinterpret_cast<const float4*>(row);  // cols w0..w0+3 (16B aligned)
                xr[i][0] = v4.x; xr[i][1] = v4.y; xr[i][2] = v4.z; xr[i][3] = v4.w;
                if (full) {
                    float2 v2 = *reinterpret_cast<const float2*>(row + 4);  // cols w0+4..w0+5
                    xr[i][4] = v2.x; xr[i][5] = v2.y;
                } else {
                    xr[i][4] = 0.f; xr[i][5] = 0.f;
                }
            }
#pragma unroll
            for (int wi = 0; wi < 4; ++wi)
#pragma unroll
                for (int i = 0; i < 3; ++i)
#pragma unroll
                    for (int j = 0; j < 3; ++j)
                        acc[bi][wi] = fmaf(xr[i][wi + j], wv[wi * 9 + i * 3 + j], acc[bi][wi]);
        }
    }

    // ---- epilogue: bias + store. out idx = ((b*O + o)*OH + h)*OW + w
    const int nw = full ? 4 : 2;
#pragma unroll
    for (int wi = 0; wi < 4; ++wi) {
        if (wi < nw) {
            const float bv = bias[((long)o * OH_ + h) * OW_ + w0 + wi];
#pragma unroll
            for (int bi = 0; bi < 8; ++bi) {
                out[(((long)(b0 + bi) * O_ + o) * OH_ + h) * OW_ + w0 + wi] = acc[bi][wi] + bv;
            }
        }
    }
}

extern "C" void kernel_launch(void* const* d_in, const int* in_sizes, int n_in,
                              void* d_out, int out_size, void* d_ws, size_t ws_size,
                              hipStream_t stream) {
    const float* x    = (const float*)d_in[0];
    const float* Wt   = (const float*)d_in[1];
    const float* bias = (const float*)d_in[2];
    float* out        = (float*)d_out;

    dim3 grid(OH_, O_);   // (h, o)
    dim3 block(64);
    lcl_kernel<<<grid, block, 0, stream>>>(x, Wt, bias, out);
}

// Round 3
// 299.368 us; speedup vs baseline: 1.0293x; 1.0293x over previous
//
#include <hip/hip_runtime.h>

// Locally connected layer:
// out[b,o,h,w] = sum_{c,i,j} x[b,c,h+i,w+j] * W[o,c,h,w,i,j] + bias[o,h,w]
// x: [32,32,64,64] f32, W: [64,32,62,62,3,3] f32, bias: [64,62,62] f32
// out: [32,64,62,62] f32
//
// W (283 MB) streams once; x (17 MB) must stay cache-resident. Grid is
// (o-group fast, h slow): all o for a given h run concurrently, so every
// co-resident block reads the same x slab (L1/L2/L3-hot) while W streams.
// Block = 256 threads = 4 waves, each wave a different o (same h) -> the 4
// waves share x in L1. Per wave: 16 w-groups x 4 batch-groups, acc[8][4].

#define C_  32
#define B_  32
#define O_  64
#define H_  64
#define W_  64
#define OH_ 62
#define OW_ 62

typedef float vfloat2 __attribute__((ext_vector_type(2)));  // native vec for nontemporal

__global__ __launch_bounds__(256)
void lcl_kernel(const float* __restrict__ x,
                const float* __restrict__ Wt,
                const float* __restrict__ bias,
                float* __restrict__ out) {
    const int h    = blockIdx.y;                 // 0..61
    const int wave = threadIdx.x >> 6;           // 0..3
    const int o    = (blockIdx.x << 2) + wave;   // 0..63
    const int lane = threadIdx.x & 63;
    const int wg   = lane & 15;                  // w0 = 4*wg
    const int bg   = lane >> 4;                  // b0 = 8*bg
    const int w0   = wg * 4;
    const int b0   = bg * 8;
    const bool full = (wg < 15);                 // wg==15 covers only w=60,61

    float acc[8][4];
#pragma unroll
    for (int bi = 0; bi < 8; ++bi)
#pragma unroll
        for (int wi = 0; wi < 4; ++wi) acc[bi][wi] = 0.f;

    // W flat idx = o*(C*OH*OW*9) + c*(OH*OW*9) + h*(OW*9) + w*9 + i*3 + j
    const long wcstride = (long)OH_ * OW_ * 9;           // 34596
    const long wbase0   = (long)o * C_ * wcstride + (long)h * (OW_ * 9) + (long)w0 * 9;
    // x flat idx = ((b*C + c)*H + (h+i))*W + col
    const long xbstride = (long)C_ * H_ * W_;            // 131072
    const long xcstride = (long)H_ * W_;                 // 4096
    const long xbase0   = (long)b0 * xbstride + (long)h * W_ + w0;

    for (int c = 0; c < C_; ++c) {
        // ---- W: 36 floats (4 w positions x 9 taps), contiguous, 8B-aligned
        const float* wp = Wt + wbase0 + (long)c * wcstride;
        float wv[36];
#pragma unroll
        for (int q = 0; q < 18; ++q) {
            if (q < 9 || full) {
                float2 v = *reinterpret_cast<const float2*>(wp + 2 * q);
                wv[2 * q] = v.x; wv[2 * q + 1] = v.y;
            } else {
                wv[2 * q] = 0.f; wv[2 * q + 1] = 0.f;
            }
        }

        const float* xp = x + xbase0 + (long)c * xcstride;
#pragma unroll
        for (int bi = 0; bi < 8; ++bi) {
            const float* xb = xp + (long)bi * xbstride;
            float xr[3][6];
#pragma unroll
            for (int i = 0; i < 3; ++i) {
                const float* row = xb + i * W_;
                float4 v4 = *reinterpret_cast<const float4*>(row);  // cols w0..w0+3 (16B aligned)
                xr[i][0] = v4.x; xr[i][1] = v4.y; xr[i][2] = v4.z; xr[i][3] = v4.w;
                if (full) {
                    float2 v2 = *reinterpret_cast<const float2*>(row + 4);  // cols w0+4..w0+5
                    xr[i][4] = v2.x; xr[i][5] = v2.y;
                } else {
                    xr[i][4] = 0.f; xr[i][5] = 0.f;
                }
            }
#pragma unroll
            for (int wi = 0; wi < 4; ++wi)
#pragma unroll
                for (int i = 0; i < 3; ++i)
#pragma unroll
                    for (int j = 0; j < 3; ++j)
                        acc[bi][wi] = fmaf(xr[i][wi + j], wv[wi * 9 + i * 3 + j], acc[bi][wi]);
        }
    }

    // ---- epilogue: bias + vfloat2 stores (row stride 248 B and w0*4 B are
    // both 8B-aligned). Nontemporal: out is never re-read, keep caches for x/W.
    const float* brow = bias + ((long)o * OH_ + h) * OW_ + w0;
    float2 bv0 = *reinterpret_cast<const float2*>(brow);
    float2 bv1;
    if (full) bv1 = *reinterpret_cast<const float2*>(brow + 2);
    else { bv1.x = 0.f; bv1.y = 0.f; }

#pragma unroll
    for (int bi = 0; bi < 8; ++bi) {
        float* orow = out + (((long)(b0 + bi) * O_ + o) * OH_ + h) * OW_ + w0;
        vfloat2 s0; s0.x = acc[bi][0] + bv0.x; s0.y = acc[bi][1] + bv0.y;
        __builtin_nontemporal_store(s0, reinterpret_cast<vfloat2*>(orow));
        if (full) {
            vfloat2 s1; s1.x = acc[bi][2] + bv1.x; s1.y = acc[bi][3] + bv1.y;
            __builtin_nontemporal_store(s1, reinterpret_cast<vfloat2*>(orow) + 1);
        }
    }
}

extern "C" void kernel_launch(void* const* d_in, const int* in_sizes, int n_in,
                              void* d_out, int out_size, void* d_ws, size_t ws_size,
                              hipStream_t stream) {
    const float* x    = (const float*)d_in[0];
    const float* Wt   = (const float*)d_in[1];
    const float* bias = (const float*)d_in[2];
    float* out        = (float*)d_out;

    dim3 grid(O_ / 4, OH_);   // (o-group fast, h slow)
    dim3 block(256);
    lcl_kernel<<<grid, block, 0, stream>>>(x, Wt, bias, out);
}